// Round 5
// baseline (3441.947 us; speedup 1.0000x reference)
//
#include <hip/hip_runtime.h>
#include <math.h>

typedef __bf16 bf16;
typedef __bf16 bf16x8 __attribute__((ext_vector_type(8)));
typedef float f32x4 __attribute__((ext_vector_type(4)));

// Problem dims
#define NQ   32
#define NN_  128
#define TT   352
#define DD   768
#define NH   8
#define HDIM 96
#define LSEQ 512
#define TSPLIT 160          // NQ + NN
#define FFD  3072
#define NLAYER 6
#define NBATCH 16

// ---------------------------------------------------------------------------
// R5 theory: MfmaUtil pinned at 16-19% across 4 schedule variants = LDS-BW
// bound, not latency. Measured b128 LDS throughput ~85 B/cyc (m134) and the
// constant 4.7M bank-conflict counter (2-way structural collision on 1KB
// wave-writes) give: 88 KB LDS traffic per block-kstep / 85 B/cyc ~= 1035 cyc
// vs 160 cyc MFMA -> 15-18% ceiling == measured. Fix: B operand bypasses LDS
// entirely -> per-lane 16B global loads (16 rows x 64B contiguous, L2-hit:
// natural round-robin gives each XCD only 3-9 B panels = L2-resident),
// 1-kstep register prefetch (unroll-by-2, named reg sets). LDS holds A only:
// traffic 88->48 KB/block-kstep -> ~28% ceiling. LDS 24/48 KB + VGPR<=128
// (launch_bounds min-waves 4) -> bt4 4 blk/CU, bt8 2 blk/CU (16 waves/CU).
// vmcnt: per step issue B[T+1] (4 loads) then A-GLOAD[T+2] (2); invariant
// wait vmcnt(6) (A[T] complete), last iter vmcnt(4). Compiler auto-waits the
// B-register consumers.
// ---------------------------------------------------------------------------
#define GLOAD(srcp, dstp)                                                     \
    __builtin_amdgcn_global_load_lds(                                         \
        (const __attribute__((address_space(1))) void*)(srcp),                \
        (__attribute__((address_space(3))) void*)(dstp), 16, 0, 0)

// ---------------------------------------------------------------------------
// 128x128 tile, 4 waves (2x2 of 64x64), BK=32, A in LDS (3-buf), B in regs.
// Optional K-split over gridDim.z: K arg = per-split K; A/Bt column offset
// z*K; C offset z*zstride; bias applied only at z==0 (ACT must be 0 if z>1).
// ---------------------------------------------------------------------------
template <int ACT>
__global__ __launch_bounds__(256, 4) void gemm_bt(
    const bf16* __restrict__ A, const bf16* __restrict__ Bt,
    bf16* __restrict__ C, const float* __restrict__ bias,
    int K, int lda, int ldb, int ldc, float alpha, int Nstore, size_t zstride)
{
    __shared__ __attribute__((aligned(16))) bf16 As[3 * 4096];

    const int z = blockIdx.z;
    A  += (size_t)z * K;
    Bt += (size_t)z * K;
    C  += (size_t)z * zstride;

    const int n0 = blockIdx.x * 128, m0 = blockIdx.y * 128;
    const int t = threadIdx.x;
    const int w = t >> 6, l = t & 63;
    const int wm = w >> 1, wn = w & 1;
    const int lr = l & 15, quad = l >> 4;

    f32x4 acc[4][4] = {};

    // A staging: wave w fills [w*1024, (w+1)*1024) of the 128x32 buffer.
    const int f0 = w * 1024 + l * 8;
    const int ra0 = f0 >> 5, ca0 = f0 & 31;
    const int ra1 = (f0 + 512) >> 5, ca1 = (f0 + 512) & 31;
    const bf16* a0 = A + (size_t)(m0 + ra0) * lda + ca0;
    const bf16* a1 = A + (size_t)(m0 + ra1) * lda + ca1;

    // B fragment row pointers: lane reads Bt[n0+wn*64+j*16+lr][k + quad*8..+8]
    const bf16* bfr0 = Bt + (size_t)(n0 + wn * 64 +  0 + lr) * ldb + quad * 8;
    const bf16* bfr1 = Bt + (size_t)(n0 + wn * 64 + 16 + lr) * ldb + quad * 8;
    const bf16* bfr2 = Bt + (size_t)(n0 + wn * 64 + 32 + lr) * ldb + quad * 8;
    const bf16* bfr3 = Bt + (size_t)(n0 + wn * 64 + 48 + lr) * ldb + quad * 8;

    const int nt = K >> 5;      // even and >= 2 at every call site

    bf16x8 be[4], bo[4];

    // prologue (issue order = vmcnt invariant): A[0], B[0]->be, A[1]
    {
        bf16* pA = &As[w * 1024];
        GLOAD(a0, pA); GLOAD(a1, pA + 512);
        be[0] = *(const bf16x8*)bfr0;
        be[1] = *(const bf16x8*)bfr1;
        be[2] = *(const bf16x8*)bfr2;
        be[3] = *(const bf16x8*)bfr3;
        pA += 4096;
        GLOAD(a0 + 32, pA); GLOAD(a1 + 32, pA + 512);
    }

    int cb = 0, wb = 2;

    auto step = [&](int T, bf16x8 (&bcur)[4], bf16x8 (&bnext)[4]) {
        if (T == nt - 1) { asm volatile("s_waitcnt vmcnt(4)" ::: "memory"); }
        else             { asm volatile("s_waitcnt vmcnt(6)" ::: "memory"); }
        __builtin_amdgcn_s_barrier();
        __builtin_amdgcn_sched_barrier(0);

        if (T + 1 < nt) {                      // B[T+1] -> bnext (4 loads)
            const int ko = (T + 1) << 5;
            bnext[0] = *(const bf16x8*)(bfr0 + ko);
            bnext[1] = *(const bf16x8*)(bfr1 + ko);
            bnext[2] = *(const bf16x8*)(bfr2 + ko);
            bnext[3] = *(const bf16x8*)(bfr3 + ko);
        }
        if (T + 2 < nt) {                      // A[T+2] -> LDS (2 GLOADs)
            const int ko = (T + 2) << 5;
            bf16* pA = &As[wb * 4096 + w * 1024];
            GLOAD(a0 + ko, pA); GLOAD(a1 + ko, pA + 512);
        }

        const int cur = cb << 12;
        bf16x8 af[4];
#pragma unroll
        for (int i = 0; i < 4; ++i)
            af[i] = *(const bf16x8*)&As[cur + (wm * 64 + i * 16 + lr) * 32 + quad * 8];

        __builtin_amdgcn_s_setprio(1);
#pragma unroll
        for (int i = 0; i < 4; ++i) {
            acc[i][0] = __builtin_amdgcn_mfma_f32_16x16x32_bf16(af[i], bcur[0], acc[i][0], 0, 0, 0);
            acc[i][1] = __builtin_amdgcn_mfma_f32_16x16x32_bf16(af[i], bcur[1], acc[i][1], 0, 0, 0);
            acc[i][2] = __builtin_amdgcn_mfma_f32_16x16x32_bf16(af[i], bcur[2], acc[i][2], 0, 0, 0);
            acc[i][3] = __builtin_amdgcn_mfma_f32_16x16x32_bf16(af[i], bcur[3], acc[i][3], 0, 0, 0);
        }
        __builtin_amdgcn_s_setprio(0);

        cb = (cb == 2) ? 0 : cb + 1;
        wb = (wb == 2) ? 0 : wb + 1;
    };

    for (int T = 0; T < nt; T += 2) {
        step(T, be, bo);
        step(T + 1, bo, be);
    }

    const bool dob = (z == 0);
#pragma unroll
    for (int i = 0; i < 4; ++i) {
        const int grow = m0 + wm * 64 + i * 16 + quad * 4;
#pragma unroll
        for (int j = 0; j < 4; ++j) {
            const int gcol = n0 + wn * 64 + j * 16 + lr;
            if (gcol >= Nstore) continue;
            float bv = (bias && dob) ? bias[gcol] : 0.0f;
#pragma unroll
            for (int r = 0; r < 4; ++r) {
                float v = acc[i][j][r] * alpha + bv;
                if (ACT == 1) v = 0.5f * v * (1.0f + erff(v * 0.70710678118654752f));
                C[(size_t)(grow + r) * ldc + gcol] = (bf16)v;
            }
        }
    }
}

// ---------------------------------------------------------------------------
// 256Mx128N tile, 8 waves (4x2 of 64x64), BK=32, A in LDS (3-buf), B in regs.
// ---------------------------------------------------------------------------
template <int ACT>
__global__ __launch_bounds__(512, 4) void gemm_bt8(
    const bf16* __restrict__ A, const bf16* __restrict__ Bt,
    bf16* __restrict__ C, const float* __restrict__ bias,
    int K, int lda, int ldb, int ldc, float alpha, int Nstore)
{
    __shared__ __attribute__((aligned(16))) bf16 As[3 * 8192];   // 3 x 256x32

    const int n0 = blockIdx.x * 128, m0 = blockIdx.y * 256;
    const int t = threadIdx.x;
    const int w = t >> 6, l = t & 63;          // w 0..7
    const int wm = w >> 1, wn = w & 1;         // wm 0..3, wn 0..1
    const int lr = l & 15, quad = l >> 4;

    f32x4 acc[4][4] = {};

    // A staged in 2 rounds of 8KB (512 thr x 16B).
    const int f0 = w * 512 + l * 8;
    const int ra0 = f0 >> 5,            ca0 = f0 & 31;   // rows 0..127
    const int ra1 = ((f0 + 4096) >> 5), ca1 = f0 & 31;   // rows 128..255
    const bf16* a0 = A + (size_t)(m0 + ra0) * lda + ca0;
    const bf16* a1 = A + (size_t)(m0 + ra1) * lda + ca1;

    const bf16* bfr0 = Bt + (size_t)(n0 + wn * 64 +  0 + lr) * ldb + quad * 8;
    const bf16* bfr1 = Bt + (size_t)(n0 + wn * 64 + 16 + lr) * ldb + quad * 8;
    const bf16* bfr2 = Bt + (size_t)(n0 + wn * 64 + 32 + lr) * ldb + quad * 8;
    const bf16* bfr3 = Bt + (size_t)(n0 + wn * 64 + 48 + lr) * ldb + quad * 8;

    const int nt = K >> 5;

    bf16x8 be[4], bo[4];

    // prologue: A[0], B[0]->be, A[1]
    {
        bf16* pA = &As[w * 512];
        GLOAD(a0, pA); GLOAD(a1, pA + 4096);
        be[0] = *(const bf16x8*)bfr0;
        be[1] = *(const bf16x8*)bfr1;
        be[2] = *(const bf16x8*)bfr2;
        be[3] = *(const bf16x8*)bfr3;
        pA += 8192;
        GLOAD(a0 + 32, pA); GLOAD(a1 + 32, pA + 4096);
    }

    int cb = 0, wb = 2;

    auto step = [&](int T, bf16x8 (&bcur)[4], bf16x8 (&bnext)[4]) {
        if (T == nt - 1) { asm volatile("s_waitcnt vmcnt(4)" ::: "memory"); }
        else             { asm volatile("s_waitcnt vmcnt(6)" ::: "memory"); }
        __builtin_amdgcn_s_barrier();
        __builtin_amdgcn_sched_barrier(0);

        if (T + 1 < nt) {
            const int ko = (T + 1) << 5;
            bnext[0] = *(const bf16x8*)(bfr0 + ko);
            bnext[1] = *(const bf16x8*)(bfr1 + ko);
            bnext[2] = *(const bf16x8*)(bfr2 + ko);
            bnext[3] = *(const bf16x8*)(bfr3 + ko);
        }
        if (T + 2 < nt) {
            const int ko = (T + 2) << 5;
            bf16* pA = &As[wb * 8192 + w * 512];
            GLOAD(a0 + ko, pA); GLOAD(a1 + ko, pA + 4096);
        }

        const int curA = cb * 8192;
        bf16x8 af[4];
#pragma unroll
        for (int i = 0; i < 4; ++i)
            af[i] = *(const bf16x8*)&As[curA + (wm * 64 + i * 16 + lr) * 32 + quad * 8];

        __builtin_amdgcn_s_setprio(1);
#pragma unroll
        for (int i = 0; i < 4; ++i) {
            acc[i][0] = __builtin_amdgcn_mfma_f32_16x16x32_bf16(af[i], bcur[0], acc[i][0], 0, 0, 0);
            acc[i][1] = __builtin_amdgcn_mfma_f32_16x16x32_bf16(af[i], bcur[1], acc[i][1], 0, 0, 0);
            acc[i][2] = __builtin_amdgcn_mfma_f32_16x16x32_bf16(af[i], bcur[2], acc[i][2], 0, 0, 0);
            acc[i][3] = __builtin_amdgcn_mfma_f32_16x16x32_bf16(af[i], bcur[3], acc[i][3], 0, 0, 0);
        }
        __builtin_amdgcn_s_setprio(0);

        cb = (cb == 2) ? 0 : cb + 1;
        wb = (wb == 2) ? 0 : wb + 1;
    };

    for (int T = 0; T < nt; T += 2) {
        step(T, be, bo);
        step(T + 1, bo, be);
    }

#pragma unroll
    for (int i = 0; i < 4; ++i) {
        const int grow = m0 + wm * 64 + i * 16 + quad * 4;
#pragma unroll
        for (int j = 0; j < 4; ++j) {
            const int gcol = n0 + wn * 64 + j * 16 + lr;
            if (gcol >= Nstore) continue;
            float bv = bias ? bias[gcol] : 0.0f;
#pragma unroll
            for (int r = 0; r < 4; ++r) {
                float v = acc[i][j][r] * alpha + bv;
                if (ACT == 1) v = 0.5f * v * (1.0f + erff(v * 0.70710678118654752f));
                C[(size_t)(grow + r) * ldc + gcol] = (bf16)v;
            }
        }
    }
}

// ---------------------------------------------------------------------------
// Flash attention with ITG prefix-LM mask (unchanged).
// ---------------------------------------------------------------------------
__global__ __launch_bounds__(256) void flash_attn(
    const bf16* __restrict__ qkv, bf16* __restrict__ ctx,
    const int* __restrict__ tatts, const int* __restrict__ gmask)
{
    __shared__ __attribute__((aligned(16))) bf16 Qs[64 * 104];
    __shared__ __attribute__((aligned(16))) bf16 Ks[64 * 104];
    __shared__ __attribute__((aligned(16))) bf16 Vs[96 * 72];   // V^T tile
    __shared__ __attribute__((aligned(16))) bf16 Ps[64 * 72];
    __shared__ int keep[512];

    const int qt = blockIdx.x;       // 0..7
    const int bh = blockIdx.y;       // 0..127
    const int b = bh >> 3, h = bh & 7;
    const int q0 = qt * 64;
    const int t = threadIdx.x;
    const int w = t >> 6, l = t & 63;
    const int lr = l & 15, quad = l >> 4;
    const float scale = 0.10206207261596577f;  // 1/sqrt(96)

    const bf16* qbase = qkv + (size_t)b * 512 * 2304 + h * 96;
    const bf16* kbase = qbase + 768;
    const bf16* vbase = qbase + 1536;

    for (int j = t; j < 512; j += 256)
        keep[j] = (j < NQ) ? 1 : (j < TSPLIT ? gmask[b * NN_ + j - NQ]
                                             : tatts[b * TT + j - TSPLIT]);

#pragma unroll
    for (int c = 0; c < 3; ++c) {
        const int idx = t * 8 + c * 2048;
        const int r = idx / 96, d = idx % 96;
        *(bf16x8*)&Qs[r * 104 + d] =
            *(const bf16x8*)&qbase[(size_t)(q0 + r) * 2304 + d];
    }
    __syncthreads();

    int ki[4];
    int ig[4];
#pragma unroll
    for (int r = 0; r < 4; ++r) {
        ig[r] = q0 + w * 16 + quad * 4 + r;
        ki[r] = keep[ig[r]];
    }

    float m_run[4] = {-1e30f, -1e30f, -1e30f, -1e30f};
    float l_run[4] = {0.f, 0.f, 0.f, 0.f};
    f32x4 oc[6] = {};

    const int JMAX = (qt < 3) ? 128 : q0;
    for (int j0 = 0; j0 <= JMAX; j0 += 64) {
        __syncthreads();
#pragma unroll
        for (int c = 0; c < 3; ++c) {
            const int idx = t * 8 + c * 2048;
            const int r = idx / 96, d = idx % 96;
            *(bf16x8*)&Ks[r * 104 + d] =
                *(const bf16x8*)&kbase[(size_t)(j0 + r) * 2304 + d];
            bf16x8 vv = *(const bf16x8*)&vbase[(size_t)(j0 + r) * 2304 + d];
#pragma unroll
            for (int jj = 0; jj < 8; ++jj)
                Vs[(d + jj) * 72 + r] = vv[jj];
        }
        __syncthreads();

        bf16x8 aq[3];
#pragma unroll
        for (int ds = 0; ds < 3; ++ds)
            aq[ds] = *(const bf16x8*)&Qs[(w * 16 + lr) * 104 + ds * 32 + quad * 8];
        f32x4 sc[4];
#pragma unroll
        for (int cb = 0; cb < 4; ++cb) {
            f32x4 a = {};
#pragma unroll
            for (int ds = 0; ds < 3; ++ds) {
                bf16x8 bk = *(const bf16x8*)&Ks[(cb * 16 + lr) * 104 + ds * 32 + quad * 8];
                a = __builtin_amdgcn_mfma_f32_16x16x32_bf16(aq[ds], bk, a, 0, 0, 0);
            }
            sc[cb] = a;
        }

        float tm[4] = {-1e30f, -1e30f, -1e30f, -1e30f};
#pragma unroll
        for (int cb = 0; cb < 4; ++cb) {
            const int jg = j0 + cb * 16 + lr;
            const int kj = keep[jg];
#pragma unroll
            for (int r = 0; r < 4; ++r) {
                const int i = ig[r];
                bool ok = ki[r] && kj;
                if (i < TSPLIT && jg >= TSPLIT) ok = false;
                if (i >= TSPLIT && jg >= TSPLIT && i < jg) ok = false;
                float s = sc[cb][r] * scale + (ok ? 0.f : -1e9f);
                sc[cb][r] = s;
                tm[r] = fmaxf(tm[r], s);
            }
        }
#pragma unroll
        for (int off = 1; off < 16; off <<= 1)
#pragma unroll
            for (int r = 0; r < 4; ++r)
                tm[r] = fmaxf(tm[r], __shfl_xor(tm[r], off));

        float alpha_[4], ts[4] = {0.f, 0.f, 0.f, 0.f};
#pragma unroll
        for (int r = 0; r < 4; ++r) {
            const float mn = fmaxf(m_run[r], tm[r]);
            alpha_[r] = __expf(m_run[r] - mn);
            m_run[r] = mn;
            l_run[r] *= alpha_[r];
        }
#pragma unroll
        for (int db = 0; db < 6; ++db)
#pragma unroll
            for (int r = 0; r < 4; ++r)
                oc[db][r] *= alpha_[r];

#pragma unroll
        for (int cb = 0; cb < 4; ++cb)
#pragma unroll
            for (int r = 0; r < 4; ++r) {
                const float p = __expf(sc[cb][r] - m_run[r]);
                ts[r] += p;
                Ps[(w * 16 + quad * 4 + r) * 72 + cb * 16 + lr] = (bf16)p;
            }
#pragma unroll
        for (int off = 1; off < 16; off <<= 1)
#pragma unroll
            for (int r = 0; r < 4; ++r)
                ts[r] += __shfl_xor(ts[r], off);
#pragma unroll
        for (int r = 0; r < 4; ++r) l_run[r] += ts[r];

        __syncthreads();

#pragma unroll
        for (int l0 = 0; l0 < 64; l0 += 32) {
            bf16x8 ap = *(const bf16x8*)&Ps[(w * 16 + lr) * 72 + l0 + quad * 8];
#pragma unroll
            for (int db = 0; db < 6; ++db) {
                bf16x8 bv = *(const bf16x8*)&Vs[(db * 16 + lr) * 72 + l0 + quad * 8];
                oc[db] = __builtin_amdgcn_mfma_f32_16x16x32_bf16(ap, bv, oc[db], 0, 0, 0);
            }
        }
    }

#pragma unroll
    for (int r = 0; r < 4; ++r) {
        const float inv = 1.f / l_run[r];
        bf16* orow = ctx + ((size_t)b * 512 + ig[r]) * 768 + h * 96;
#pragma unroll
        for (int db = 0; db < 6; ++db)
            orow[db * 16 + lr] = (bf16)(oc[db][r] * inv);
    }
}

// ---------------------------------------------------------------------------
// transpose fp32 weight [R][C] -> bf16 [C][R]
// ---------------------------------------------------------------------------
__global__ void transpose_w(const float* __restrict__ in, bf16* __restrict__ out,
                            int R, int C)
{
    __shared__ bf16 tile[32][33];
    const int c0 = blockIdx.x * 32, r0 = blockIdx.y * 32;
    const int tx = threadIdx.x & 31, ty = threadIdx.x >> 5;
    for (int i = ty; i < 32; i += 8)
        tile[i][tx] = (bf16)in[(size_t)(r0 + i) * C + c0 + tx];
    __syncthreads();
    for (int i = ty; i < 32; i += 8)
        out[(size_t)(c0 + i) * R + r0 + tx] = tile[tx][i];
}

// fp32 -> bf16 elementwise
__global__ void cvt_bf16(const float* __restrict__ in, bf16* __restrict__ out, int n)
{
    const int idx = blockIdx.x * 256 + threadIdx.x;
    if (idx < n) out[idx] = (bf16)in[idx];
}

// ---------------------------------------------------------------------------
// reductions / LN
// ---------------------------------------------------------------------------
__device__ __forceinline__ void block_reduce_2(float& a, float& b)
{
#pragma unroll
    for (int off = 32; off; off >>= 1) {
        a += __shfl_xor(a, off);
        b += __shfl_xor(b, off);
    }
    __shared__ float sa[4], sb[4];
    const int w = threadIdx.x >> 6;
    if ((threadIdx.x & 63) == 0) { sa[w] = a; sb[w] = b; }
    __syncthreads();
    a = sa[0] + sa[1] + sa[2] + sa[3];
    b = sb[0] + sb[1] + sb[2] + sb[3];
}

// x[row] = LN(concat_src(row) + pos[l] + tok); fp32 inputs, bf16 out
__global__ void embed_ln(const float* __restrict__ qtok, const bf16* __restrict__ gfeat,
                         const float* __restrict__ text, const float* __restrict__ pos,
                         const float* __restrict__ tok, const float* __restrict__ g,
                         const float* __restrict__ bb, bf16* __restrict__ x)
{
    const int row = blockIdx.x;           // b*512 + l
    const int l = row & 511, b = row >> 9;
    const int t = threadIdx.x;

    float vals[3], s = 0.f, sq = 0.f;
#pragma unroll
    for (int c = 0; c < 3; ++c) {
        const int d = t + c * 256;
        float base;
        if (l < NQ)           base = qtok[(size_t)l * DD + d];
        else if (l < TSPLIT)  base = (float)gfeat[((size_t)b * NN_ + (l - NQ)) * DD + d];
        else                  base = text[((size_t)b * TT + (l - TSPLIT)) * DD + d];
        float v = base + pos[(size_t)l * DD + d] + tok[d];
        vals[c] = v; s += v; sq += v * v;
    }
    block_reduce_2(s, sq);
    const float mean = s * (1.f / 768.f);
    const float var = sq * (1.f / 768.f) - mean * mean;
    const float rs = rsqrtf(var + 1e-12f);
    bf16* o = x + (size_t)row * DD;
#pragma unroll
    for (int c = 0; c < 3; ++c) {
        const int d = t + c * 256;
        o[d] = (bf16)((vals[c] - mean) * rs * g[d] + bb[d]);
    }
}

// out[row] = LN(X[row] + Y[row] + Z[row]); safe for out==X; fp32 gains
__global__ void ln_rows3(const bf16* __restrict__ X, const bf16* __restrict__ Y,
                         const bf16* __restrict__ Z, bf16* __restrict__ Out,
                         const float* __restrict__ g, const float* __restrict__ bb)
{
    const int row = blockIdx.x;
    const int t = threadIdx.x;
    const bf16* xr = X + (size_t)row * DD;
    const bf16* yr = Y + (size_t)row * DD;
    const bf16* zr = Z + (size_t)row * DD;
    float vals[3], s = 0.f, sq = 0.f;
#pragma unroll
    for (int c = 0; c < 3; ++c) {
        const int d = t + c * 256;
        float v = (float)xr[d] + (float)yr[d] + (float)zr[d];
        vals[c] = v; s += v; sq += v * v;
    }
    block_reduce_2(s, sq);
    const float mean = s * (1.f / 768.f);
    const float var = sq * (1.f / 768.f) - mean * mean;
    const float rs = rsqrtf(var + 1e-12f);
    bf16* o = Out + (size_t)row * DD;
#pragma unroll
    for (int c = 0; c < 3; ++c) {
        const int d = t + c * 256;
        o[d] = (bf16)((vals[c] - mean) * rs * g[d] + bb[d]);
    }
}

// d_out[b][t][d] = x[b][TSPLIT+t][d]  (fp32 out)
__global__ void copy_out(const bf16* __restrict__ x, float* __restrict__ out)
{
    const size_t idx = (size_t)blockIdx.x * 256 + threadIdx.x;   // < 16*352*768
    const int d = idx % DD;
    const size_t row = idx / DD;
    const int t = row % TT;
    const int b = row / TT;
    out[idx] = (float)x[((size_t)b * LSEQ + TSPLIT + t) * DD + d];
}

// ---------------------------------------------------------------------------
// host side
// ---------------------------------------------------------------------------
static void launch_gemm(const bf16* A, const bf16* Bt, bf16* C, const float* bias,
                        int M, int K, int lda, int ldb, int ldc,
                        float alpha, int Nstore, int act, int ksplit, size_t zstride,
                        hipStream_t stream)
{
    dim3 grid((Nstore + 127) / 128, M / 128, ksplit);
    if (act)
        gemm_bt<1><<<grid, 256, 0, stream>>>(A, Bt, C, bias, K / ksplit, lda, ldb, ldc, alpha, Nstore, zstride);
    else
        gemm_bt<0><<<grid, 256, 0, stream>>>(A, Bt, C, bias, K / ksplit, lda, ldb, ldc, alpha, Nstore, zstride);
}

static void launch_gemm8(const bf16* A, const bf16* Bt, bf16* C, const float* bias,
                         int M, int K, int lda, int ldb, int ldc,
                         float alpha, int Nstore, int act, hipStream_t stream)
{
    dim3 grid((Nstore + 127) / 128, M / 256, 1);
    if (act)
        gemm_bt8<1><<<grid, 512, 0, stream>>>(A, Bt, C, bias, K, lda, ldb, ldc, alpha, Nstore);
    else
        gemm_bt8<0><<<grid, 512, 0, stream>>>(A, Bt, C, bias, K, lda, ldb, ldc, alpha, Nstore);
}

extern "C" void kernel_launch(void* const* d_in, const int* in_sizes, int n_in,
                              void* d_out, int out_size, void* d_ws, size_t ws_size,
                              hipStream_t stream)
{
    // Reference dtypes: all float32 except text_atts / graph_mask (int32).
    const float* gnf     = (const float*)d_in[0];
    const float* text    = (const float*)d_in[1];
    const int*   tatts   = (const int*)d_in[2];
    const int*   gmask   = (const int*)d_in[3];
    const float* qtok    = (const float*)d_in[4];
    const float* gproj_w = (const float*)d_in[5];
    const float* gproj_b = (const float*)d_in[6];
    const float* pos     = (const float*)d_in[7];
    const float* tok     = (const float*)d_in[8];
    const float* eg      = (const float*)d_in[9];
    const float* eb      = (const float*)d_in[10];
    const float* qkv_w   = (const float*)d_in[11];
    const float* qkv_b   = (const float*)d_in[12];
    const float* ao_w    = (const float*)d_in[13];
    const float* ao_b    = (const float*)d_in[14];
    const float* ln1g    = (const float*)d_in[15];
    const float* ln1b    = (const float*)d_in[16];
    const float* ff1_w   = (const float*)d_in[17];
    const float* ff1_b   = (const float*)d_in[18];
    const float* ff2_w   = (const float*)d_in[19];
    const float* ff2_b   = (const float*)d_in[20];
    const float* ln2g    = (const float*)d_in[21];
    const float* ln2b    = (const float*)d_in[22];
    float* out = (float*)d_out;

    // ws layout (bf16 elems): u-region: qkvb (attn) / hbuf (ffn), disjoint in
    // time. t2 sits past hbuf so split-K z=1 writes never alias the A operand.
    bf16* ws   = (bf16*)d_ws;
    bf16* wt1  = ws;                    // 2,359,296
    bf16* wt2  = wt1 + 2359296;         // 2,359,296
    bf16* x    = wt2 + 2359296;         // 6,291,456
    bf16* ctx  = x   + 6291456;         // 6,291,456
    bf16* t1   = ctx + 6291456;         // 6,291,456
    bf16* u    = t1  + 6291456;         // 25,165,824
    bf16* qkvb = u;                     //   18,874,368 (attn phase)
    bf16* hbuf = u;                     //   25,165,824 (ffn phase)
    bf16* t2   = u   + 25165824;        // 6,291,456 (split-K partial z=1)
    bf16* gfeat = t1;                   //    1,572,864 (pre-loop)
    bf16* gnfb  = u;                    //    1,572,864 (pre-loop)
    const size_t ZST = (size_t)(t2 - t1);   // 31,457,280 elems

    dim3 blk(256);

    // graph projection: gfeat[2048,768] = bf16(gnf) @ bf16(gproj_w) + b
    cvt_bf16<<<6144, blk, 0, stream>>>(gnf, gnfb, 1572864);
    transpose_w<<<dim3(24, 24), blk, 0, stream>>>(gproj_w, wt1, 768, 768);
    launch_gemm(gnfb, wt1, gfeat, gproj_b, 2048, 768, 768, 768, 768,
                1.f, 768, 0, 1, 0, stream);
    embed_ln<<<8192, blk, 0, stream>>>(qtok, gfeat, text, pos, tok, eg, eb, x);

    for (int i = 0; i < NLAYER; ++i) {
        // qkv = x @ qkv_w[i] + b   [8192, 2304]   (8-wave kernel)
        transpose_w<<<dim3(72, 24), blk, 0, stream>>>(
            qkv_w + (size_t)i * 768 * 2304, wt1, 768, 2304);
        launch_gemm8(x, wt1, qkvb, qkv_b + i * 2304,
                     8192, 768, 768, 768, 2304, 1.f, 2304, 0, stream);
        // fused attention -> ctx [8192, 768]
        flash_attn<<<dim3(8, 128), blk, 0, stream>>>(qkvb, ctx, tatts, gmask);
        // t1/t2 = split-K partials of ctx @ ao_w[i] (+ b at z=0)
        transpose_w<<<dim3(24, 24), blk, 0, stream>>>(
            ao_w + (size_t)i * 589824, wt1, 768, 768);
        launch_gemm(ctx, wt1, t1, ao_b + i * 768,
                    8192, 768, 768, 768, 768, 1.f, 768, 0, 2, ZST, stream);
        ln_rows3<<<8192, blk, 0, stream>>>(x, t1, t2, x, ln1g + i * 768, ln1b + i * 768);

        // ffn
        transpose_w<<<dim3(96, 24), blk, 0, stream>>>(
            ff1_w + (size_t)i * 2359296, wt1, 768, 3072);
        transpose_w<<<dim3(24, 96), blk, 0, stream>>>(
            ff2_w + (size_t)i * 2359296, wt2, 3072, 768);
        launch_gemm8(x, wt1, hbuf, ff1_b + i * 3072,
                     8192, 768, 768, 768, 3072, 1.f, 3072, 1, stream);
        launch_gemm(hbuf, wt2, t1, ff2_b + i * 768,
                    8192, 3072, 3072, 3072, 768, 1.f, 768, 0, 2, ZST, stream);
        ln_rows3<<<8192, blk, 0, stream>>>(x, t1, t2, x, ln2g + i * 768, ln2b + i * 768);
    }

    copy_out<<<16896, blk, 0, stream>>>(x, out);

    (void)in_sizes; (void)n_in; (void)out_size; (void)ws_size;
}

// Round 7
// 2038.054 us; speedup vs baseline: 1.6888x; 1.6888x over previous
//
#include <hip/hip_runtime.h>
#include <math.h>

typedef __bf16 bf16;
typedef __bf16 bf16x8 __attribute__((ext_vector_type(8)));
typedef __bf16 bf16x4 __attribute__((ext_vector_type(4)));
typedef float f32x4 __attribute__((ext_vector_type(4)));

// Problem dims
#define NQ   32
#define NN_  128
#define TT   352
#define DD   768
#define NH   8
#define HDIM 96
#define LSEQ 512
#define TSPLIT 160          // NQ + NN
#define FFD  3072
#define NLAYER 6
#define NBATCH 16

// ---------------------------------------------------------------------------
// R7 = R6 resubmitted verbatim (R6 bench was an infra failure: "container
// failed twice", no compile/test diagnostics; source re-audited for OOB /
// LDS overflow / grid mismatches — none found).
// R6 rationale: R5's B-in-registers regressed 70% -> full revert to R4 GEMMs
// (A+B in LDS, 3-buffer counted-vmcnt; best measured = 2141us), then attack
// the unprofiled periphery:
//  * qkv on the 128^2 kernel (1152 blocks/~768 slots = 1.5 gens vs bt8's
//    576/512 = effective 2 gens).
//  * ln_rows3: wave-per-row, bf16x8+bf16x4 vector loads, shuffle-only reduce
//    (scalar bf16 loads are 2-2.5x slower — Common-mistake #2; x12 dispatches).
//  * copy_out vectorized x8.
//  * 4 weight-transpose launches/layer merged into 1 (launch overhead).
//  * T5 setprio around attn MFMA clusters (+4-7%, m191).
// SQ_LDS_BANK_CONFLICT 4,718,592 in GEMMs = inherent global_load_lds write
// serialization — not a read conflict; do not chase it.
// ---------------------------------------------------------------------------
#define GLOAD(srcp, dstp)                                                     \
    __builtin_amdgcn_global_load_lds(                                         \
        (const __attribute__((address_space(1))) void*)(srcp),                \
        (__attribute__((address_space(3))) void*)(dstp), 16, 0, 0)

// ---------------------------------------------------------------------------
// 128x128 tile, 4 waves, BK=32, 3-buffer counted-vmcnt pipeline (R4-exact).
// Optional K-split over gridDim.z: K arg = per-split K; A/Bt column offset
// z*K; C offset z*zstride; bias applied only at z==0 (ACT must be 0 if z>1).
// ---------------------------------------------------------------------------
template <int ACT>
__global__ __launch_bounds__(256) void gemm_bt(
    const bf16* __restrict__ A, const bf16* __restrict__ Bt,
    bf16* __restrict__ C, const float* __restrict__ bias,
    int K, int lda, int ldb, int ldc, float alpha, int Nstore, size_t zstride)
{
    __shared__ __attribute__((aligned(16))) bf16 As[3 * 4096];
    __shared__ __attribute__((aligned(16))) bf16 Bs[3 * 4096];

    const int z = blockIdx.z;
    A  += (size_t)z * K;
    Bt += (size_t)z * K;
    C  += (size_t)z * zstride;

    const int n0 = blockIdx.x * 128, m0 = blockIdx.y * 128;
    const int t = threadIdx.x;
    const int w = t >> 6, l = t & 63;
    const int wm = w >> 1, wn = w & 1;
    const int lr = l & 15, quad = l >> 4;

    f32x4 acc[4][4] = {};

    const int f0 = w * 1024 + l * 8;
    const int ra0 = f0 >> 5, ca0 = f0 & 31;
    const int ra1 = (f0 + 512) >> 5, ca1 = (f0 + 512) & 31;
    const bf16* a0 = A  + (size_t)(m0 + ra0) * lda + ca0;
    const bf16* a1 = A  + (size_t)(m0 + ra1) * lda + ca1;
    const bf16* b0 = Bt + (size_t)(n0 + ra0) * ldb + ca0;
    const bf16* b1 = Bt + (size_t)(n0 + ra1) * ldb + ca1;

    const int nt = K >> 5;              // >= 3 for all call sites

    // prologue: stage tiles 0,1 into buffers 0,1
    {
        bf16* pA = &As[w * 1024];
        bf16* pB = &Bs[w * 1024];
        GLOAD(a0, pA);        GLOAD(a1, pA + 512);
        GLOAD(b0, pB);        GLOAD(b1, pB + 512);
        pA += 4096;  pB += 4096;
        GLOAD(a0 + 32, pA);   GLOAD(a1 + 32, pA + 512);
        GLOAD(b0 + 32, pB);   GLOAD(b1 + 32, pB + 512);
    }

    int cb = 0, wb = 2;
    for (int T = 0; T < nt; ++T) {
        if (T == nt - 1) {
            asm volatile("s_waitcnt vmcnt(0)" ::: "memory");
        } else {
            asm volatile("s_waitcnt vmcnt(4)" ::: "memory");
        }
        __builtin_amdgcn_s_barrier();
        __builtin_amdgcn_sched_barrier(0);

        if (T + 2 < nt) {
            const int k0 = (T + 2) << 5;
            bf16* pA = &As[wb * 4096 + w * 1024];
            bf16* pB = &Bs[wb * 4096 + w * 1024];
            GLOAD(a0 + k0, pA);   GLOAD(a1 + k0, pA + 512);
            GLOAD(b0 + k0, pB);   GLOAD(b1 + k0, pB + 512);
        }

        const int cur = cb << 12;
        bf16x8 af[4], bf_[4];
#pragma unroll
        for (int i = 0; i < 4; ++i)
            af[i] = *(const bf16x8*)&As[cur + (wm * 64 + i * 16 + lr) * 32 + quad * 8];
#pragma unroll
        for (int j = 0; j < 4; ++j)
            bf_[j] = *(const bf16x8*)&Bs[cur + (wn * 64 + j * 16 + lr) * 32 + quad * 8];
#pragma unroll
        for (int i = 0; i < 4; ++i)
#pragma unroll
            for (int j = 0; j < 4; ++j)
                acc[i][j] = __builtin_amdgcn_mfma_f32_16x16x32_bf16(af[i], bf_[j], acc[i][j], 0, 0, 0);

        cb = (cb == 2) ? 0 : cb + 1;
        wb = (wb == 2) ? 0 : wb + 1;
    }

    const bool dob = (z == 0);
#pragma unroll
    for (int i = 0; i < 4; ++i) {
        const int grow = m0 + wm * 64 + i * 16 + quad * 4;
#pragma unroll
        for (int j = 0; j < 4; ++j) {
            const int gcol = n0 + wn * 64 + j * 16 + lr;
            if (gcol >= Nstore) continue;
            float bv = (bias && dob) ? bias[gcol] : 0.0f;
#pragma unroll
            for (int r = 0; r < 4; ++r) {
                float v = acc[i][j][r] * alpha + bv;
                if (ACT == 1) v = 0.5f * v * (1.0f + erff(v * 0.70710678118654752f));
                C[(size_t)(grow + r) * ldc + gcol] = (bf16)v;
            }
        }
    }
}

// ---------------------------------------------------------------------------
// 256Mx128N tile, 8 waves (4x2 of 64x64), BK=32, 3-buffer counted-vmcnt
// (R4-exact). Used for FF1.
// ---------------------------------------------------------------------------
template <int ACT>
__global__ __launch_bounds__(512) void gemm_bt8(
    const bf16* __restrict__ A, const bf16* __restrict__ Bt,
    bf16* __restrict__ C, const float* __restrict__ bias,
    int K, int lda, int ldb, int ldc, float alpha, int Nstore)
{
    __shared__ __attribute__((aligned(16))) bf16 As[3 * 8192];   // 3 x 256x32
    __shared__ __attribute__((aligned(16))) bf16 Bs[3 * 4096];   // 3 x 128x32

    const int n0 = blockIdx.x * 128, m0 = blockIdx.y * 256;
    const int t = threadIdx.x;
    const int w = t >> 6, l = t & 63;          // w 0..7
    const int wm = w >> 1, wn = w & 1;         // wm 0..3, wn 0..1
    const int lr = l & 15, quad = l >> 4;

    f32x4 acc[4][4] = {};

    const int f0 = w * 512 + l * 8;
    const int ra0 = f0 >> 5,            ca0 = f0 & 31;   // rows 0..127
    const int ra1 = ((f0 + 4096) >> 5);                  // rows 128..255
    const bf16* a0 = A  + (size_t)(m0 + ra0) * lda + ca0;
    const bf16* a1 = A  + (size_t)(m0 + ra1) * lda + ca0;
    const bf16* b0 = Bt + (size_t)(n0 + ra0) * ldb + ca0;

    const int nt = K >> 5;

    // prologue: tiles 0,1
    {
        bf16* pA = &As[w * 512];
        bf16* pB = &Bs[w * 512];
        GLOAD(a0, pA);        GLOAD(a1, pA + 4096);   GLOAD(b0, pB);
        pA += 8192;  pB += 4096;
        GLOAD(a0 + 32, pA);   GLOAD(a1 + 32, pA + 4096);  GLOAD(b0 + 32, pB);
    }

    int cb = 0, wb = 2;
    for (int T = 0; T < nt; ++T) {
        if (T == nt - 1) {
            asm volatile("s_waitcnt vmcnt(0)" ::: "memory");
        } else {
            asm volatile("s_waitcnt vmcnt(3)" ::: "memory");
        }
        __builtin_amdgcn_s_barrier();
        __builtin_amdgcn_sched_barrier(0);

        if (T + 2 < nt) {
            const int k0 = (T + 2) << 5;
            bf16* pA = &As[wb * 8192 + w * 512];
            bf16* pB = &Bs[wb * 4096 + w * 512];
            GLOAD(a0 + k0, pA);  GLOAD(a1 + k0, pA + 4096);  GLOAD(b0 + k0, pB);
        }

        const int curA = cb * 8192, curB = cb * 4096;
        bf16x8 af[4], bf_[4];
#pragma unroll
        for (int i = 0; i < 4; ++i)
            af[i] = *(const bf16x8*)&As[curA + (wm * 64 + i * 16 + lr) * 32 + quad * 8];
#pragma unroll
        for (int j = 0; j < 4; ++j)
            bf_[j] = *(const bf16x8*)&Bs[curB + (wn * 64 + j * 16 + lr) * 32 + quad * 8];

        __builtin_amdgcn_s_setprio(1);
#pragma unroll
        for (int i = 0; i < 4; ++i) {
            acc[i][0] = __builtin_amdgcn_mfma_f32_16x16x32_bf16(af[i], bf_[0], acc[i][0], 0, 0, 0);
            acc[i][1] = __builtin_amdgcn_mfma_f32_16x16x32_bf16(af[i], bf_[1], acc[i][1], 0, 0, 0);
            acc[i][2] = __builtin_amdgcn_mfma_f32_16x16x32_bf16(af[i], bf_[2], acc[i][2], 0, 0, 0);
            acc[i][3] = __builtin_amdgcn_mfma_f32_16x16x32_bf16(af[i], bf_[3], acc[i][3], 0, 0, 0);
        }
        __builtin_amdgcn_s_setprio(0);

        cb = (cb == 2) ? 0 : cb + 1;
        wb = (wb == 2) ? 0 : wb + 1;
    }

#pragma unroll
    for (int i = 0; i < 4; ++i) {
        const int grow = m0 + wm * 64 + i * 16 + quad * 4;
#pragma unroll
        for (int j = 0; j < 4; ++j) {
            const int gcol = n0 + wn * 64 + j * 16 + lr;
            if (gcol >= Nstore) continue;
            float bv = bias ? bias[gcol] : 0.0f;
#pragma unroll
            for (int r = 0; r < 4; ++r) {
                float v = acc[i][j][r] * alpha + bv;
                if (ACT == 1) v = 0.5f * v * (1.0f + erff(v * 0.70710678118654752f));
                C[(size_t)(grow + r) * ldc + gcol] = (bf16)v;
            }
        }
    }
}

// ---------------------------------------------------------------------------
// Flash attention with ITG prefix-LM mask (R4 + T5 setprio).
// ---------------------------------------------------------------------------
__global__ __launch_bounds__(256) void flash_attn(
    const bf16* __restrict__ qkv, bf16* __restrict__ ctx,
    const int* __restrict__ tatts, const int* __restrict__ gmask)
{
    __shared__ __attribute__((aligned(16))) bf16 Qs[64 * 104];
    __shared__ __attribute__((aligned(16))) bf16 Ks[64 * 104];
    __shared__ __attribute__((aligned(16))) bf16 Vs[96 * 72];   // V^T tile
    __shared__ __attribute__((aligned(16))) bf16 Ps[64 * 72];
    __shared__ int keep[512];

    const int qt = blockIdx.x;       // 0..7
    const int bh = blockIdx.y;       // 0..127
    const int b = bh >> 3, h = bh & 7;
    const int q0 = qt * 64;
    const int t = threadIdx.x;
    const int w = t >> 6, l = t & 63;
    const int lr = l & 15, quad = l >> 4;
    const float scale = 0.10206207261596577f;  // 1/sqrt(96)

    const bf16* qbase = qkv + (size_t)b * 512 * 2304 + h * 96;
    const bf16* kbase = qbase + 768;
    const bf16* vbase = qbase + 1536;

    for (int j = t; j < 512; j += 256)
        keep[j] = (j < NQ) ? 1 : (j < TSPLIT ? gmask[b * NN_ + j - NQ]
                                             : tatts[b * TT + j - TSPLIT]);

#pragma unroll
    for (int c = 0; c < 3; ++c) {
        const int idx = t * 8 + c * 2048;
        const int r = idx / 96, d = idx % 96;
        *(bf16x8*)&Qs[r * 104 + d] =
            *(const bf16x8*)&qbase[(size_t)(q0 + r) * 2304 + d];
    }
    __syncthreads();

    int ki[4];
    int ig[4];
#pragma unroll
    for (int r = 0; r < 4; ++r) {
        ig[r] = q0 + w * 16 + quad * 4 + r;
        ki[r] = keep[ig[r]];
    }

    float m_run[4] = {-1e30f, -1e30f, -1e30f, -1e30f};
    float l_run[4] = {0.f, 0.f, 0.f, 0.f};
    f32x4 oc[6] = {};

    const int JMAX = (qt < 3) ? 128 : q0;
    for (int j0 = 0; j0 <= JMAX; j0 += 64) {
        __syncthreads();
#pragma unroll
        for (int c = 0; c < 3; ++c) {
            const int idx = t * 8 + c * 2048;
            const int r = idx / 96, d = idx % 96;
            *(bf16x8*)&Ks[r * 104 + d] =
                *(const bf16x8*)&kbase[(size_t)(j0 + r) * 2304 + d];
            bf16x8 vv = *(const bf16x8*)&vbase[(size_t)(j0 + r) * 2304 + d];
#pragma unroll
            for (int jj = 0; jj < 8; ++jj)
                Vs[(d + jj) * 72 + r] = vv[jj];
        }
        __syncthreads();

        bf16x8 aq[3];
#pragma unroll
        for (int ds = 0; ds < 3; ++ds)
            aq[ds] = *(const bf16x8*)&Qs[(w * 16 + lr) * 104 + ds * 32 + quad * 8];
        f32x4 sc[4];
        __builtin_amdgcn_s_setprio(1);
#pragma unroll
        for (int cb = 0; cb < 4; ++cb) {
            f32x4 a = {};
#pragma unroll
            for (int ds = 0; ds < 3; ++ds) {
                bf16x8 bk = *(const bf16x8*)&Ks[(cb * 16 + lr) * 104 + ds * 32 + quad * 8];
                a = __builtin_amdgcn_mfma_f32_16x16x32_bf16(aq[ds], bk, a, 0, 0, 0);
            }
            sc[cb] = a;
        }
        __builtin_amdgcn_s_setprio(0);

        float tm[4] = {-1e30f, -1e30f, -1e30f, -1e30f};
#pragma unroll
        for (int cb = 0; cb < 4; ++cb) {
            const int jg = j0 + cb * 16 + lr;
            const int kj = keep[jg];
#pragma unroll
            for (int r = 0; r < 4; ++r) {
                const int i = ig[r];
                bool ok = ki[r] && kj;
                if (i < TSPLIT && jg >= TSPLIT) ok = false;
                if (i >= TSPLIT && jg >= TSPLIT && i < jg) ok = false;
                float s = sc[cb][r] * scale + (ok ? 0.f : -1e9f);
                sc[cb][r] = s;
                tm[r] = fmaxf(tm[r], s);
            }
        }
#pragma unroll
        for (int off = 1; off < 16; off <<= 1)
#pragma unroll
            for (int r = 0; r < 4; ++r)
                tm[r] = fmaxf(tm[r], __shfl_xor(tm[r], off));

        float alpha_[4], ts[4] = {0.f, 0.f, 0.f, 0.f};
#pragma unroll
        for (int r = 0; r < 4; ++r) {
            const float mn = fmaxf(m_run[r], tm[r]);
            alpha_[r] = __expf(m_run[r] - mn);
            m_run[r] = mn;
            l_run[r] *= alpha_[r];
        }
#pragma unroll
        for (int db = 0; db < 6; ++db)
#pragma unroll
            for (int r = 0; r < 4; ++r)
                oc[db][r] *= alpha_[r];

#pragma unroll
        for (int cb = 0; cb < 4; ++cb)
#pragma unroll
            for (int r = 0; r < 4; ++r) {
                const float p = __expf(sc[cb][r] - m_run[r]);
                ts[r] += p;
                Ps[(w * 16 + quad * 4 + r) * 72 + cb * 16 + lr] = (bf16)p;
            }
#pragma unroll
        for (int off = 1; off < 16; off <<= 1)
#pragma unroll
            for (int r = 0; r < 4; ++r)
                ts[r] += __shfl_xor(ts[r], off);
#pragma unroll
        for (int r = 0; r < 4; ++r) l_run[r] += ts[r];

        __syncthreads();

        __builtin_amdgcn_s_setprio(1);
#pragma unroll
        for (int l0 = 0; l0 < 64; l0 += 32) {
            bf16x8 ap = *(const bf16x8*)&Ps[(w * 16 + lr) * 72 + l0 + quad * 8];
#pragma unroll
            for (int db = 0; db < 6; ++db) {
                bf16x8 bv = *(const bf16x8*)&Vs[(db * 16 + lr) * 72 + l0 + quad * 8];
                oc[db] = __builtin_amdgcn_mfma_f32_16x16x32_bf16(ap, bv, oc[db], 0, 0, 0);
            }
        }
        __builtin_amdgcn_s_setprio(0);
    }

#pragma unroll
    for (int r = 0; r < 4; ++r) {
        const float inv = 1.f / l_run[r];
        bf16* orow = ctx + ((size_t)b * 512 + ig[r]) * 768 + h * 96;
#pragma unroll
        for (int db = 0; db < 6; ++db)
            orow[db * 16 + lr] = (bf16)(oc[db][r] * inv);
    }
}

// ---------------------------------------------------------------------------
// weight transposes: fp32 [R][C] -> bf16 [C][R]
// ---------------------------------------------------------------------------
__device__ __forceinline__ void tr_tile(const float* __restrict__ in,
                                        bf16* __restrict__ out,
                                        int R, int C, int bx, int by)
{
    __shared__ bf16 tile[32][33];
    const int c0 = bx * 32, r0 = by * 32;
    const int tx = threadIdx.x & 31, ty = threadIdx.x >> 5;
    for (int i = ty; i < 32; i += 8)
        tile[i][tx] = (bf16)in[(size_t)(r0 + i) * C + c0 + tx];
    __syncthreads();
    for (int i = ty; i < 32; i += 8)
        out[(size_t)(c0 + i) * R + r0 + tx] = tile[tx][i];
}

__global__ void transpose_w(const float* __restrict__ in, bf16* __restrict__ out,
                            int R, int C)
{
    tr_tile(in, out, R, C, blockIdx.x, blockIdx.y);
}

// all 4 per-layer weights in one launch. ranges:
// [0,1728) qkv 768x2304 ; [1728,2304) ao 768x768 ;
// [2304,4608) ff1 768x3072 ; [4608,6912) ff2 3072x768
__global__ void transpose_all(const float* __restrict__ qw, const float* __restrict__ aw,
                              const float* __restrict__ f1, const float* __restrict__ f2,
                              bf16* __restrict__ oq, bf16* __restrict__ oa,
                              bf16* __restrict__ o1, bf16* __restrict__ o2)
{
    int id = blockIdx.x;
    if (id < 1728) {
        tr_tile(qw, oq, 768, 2304, id % 72, id / 72);
    } else if (id < 2304) {
        id -= 1728;
        tr_tile(aw, oa, 768, 768, id % 24, id / 24);
    } else if (id < 4608) {
        id -= 2304;
        tr_tile(f1, o1, 768, 3072, id % 96, id / 96);
    } else {
        id -= 4608;
        tr_tile(f2, o2, 3072, 768, id % 24, id / 24);
    }
}

// fp32 -> bf16 elementwise
__global__ void cvt_bf16(const float* __restrict__ in, bf16* __restrict__ out, int n)
{
    const int idx = blockIdx.x * 256 + threadIdx.x;
    if (idx < n) out[idx] = (bf16)in[idx];
}

// ---------------------------------------------------------------------------
// reductions / LN
// ---------------------------------------------------------------------------
__device__ __forceinline__ void block_reduce_2(float& a, float& b)
{
#pragma unroll
    for (int off = 32; off; off >>= 1) {
        a += __shfl_xor(a, off);
        b += __shfl_xor(b, off);
    }
    __shared__ float sa[4], sb[4];
    const int w = threadIdx.x >> 6;
    if ((threadIdx.x & 63) == 0) { sa[w] = a; sb[w] = b; }
    __syncthreads();
    a = sa[0] + sa[1] + sa[2] + sa[3];
    b = sb[0] + sb[1] + sb[2] + sb[3];
}

// x[row] = LN(concat_src(row) + pos[l] + tok); fp32 inputs, bf16 out
__global__ void embed_ln(const float* __restrict__ qtok, const bf16* __restrict__ gfeat,
                         const float* __restrict__ text, const float* __restrict__ pos,
                         const float* __restrict__ tok, const float* __restrict__ g,
                         const float* __restrict__ bb, bf16* __restrict__ x)
{
    const int row = blockIdx.x;           // b*512 + l
    const int l = row & 511, b = row >> 9;
    const int t = threadIdx.x;

    float vals[3], s = 0.f, sq = 0.f;
#pragma unroll
    for (int c = 0; c < 3; ++c) {
        const int d = t + c * 256;
        float base;
        if (l < NQ)           base = qtok[(size_t)l * DD + d];
        else if (l < TSPLIT)  base = (float)gfeat[((size_t)b * NN_ + (l - NQ)) * DD + d];
        else                  base = text[((size_t)b * TT + (l - TSPLIT)) * DD + d];
        float v = base + pos[(size_t)l * DD + d] + tok[d];
        vals[c] = v; s += v; sq += v * v;
    }
    block_reduce_2(s, sq);
    const float mean = s * (1.f / 768.f);
    const float var = sq * (1.f / 768.f) - mean * mean;
    const float rs = rsqrtf(var + 1e-12f);
    bf16* o = x + (size_t)row * DD;
#pragma unroll
    for (int c = 0; c < 3; ++c) {
        const int d = t + c * 256;
        o[d] = (bf16)((vals[c] - mean) * rs * g[d] + bb[d]);
    }
}

// out[row] = LN(X[row] + Y[row] + Z[row]); wave-per-row, vectorized (G13).
// 1 wave owns 1 row (768 = 64*8 + 64*4); shuffle-only reduce; safe for out==X.
__global__ __launch_bounds__(256) void ln_rows3(
    const bf16* __restrict__ X, const bf16* __restrict__ Y,
    const bf16* __restrict__ Z, bf16* __restrict__ Out,
    const float* __restrict__ g, const float* __restrict__ bb)
{
    const int w = threadIdx.x >> 6, l = threadIdx.x & 63;
    const int row = (blockIdx.x << 2) + w;
    const bf16* xr = X + (size_t)row * DD;
    const bf16* yr = Y + (size_t)row * DD;
    const bf16* zr = Z + (size_t)row * DD;

    bf16x8 a0 = *(const bf16x8*)&xr[l * 8];
    bf16x8 b0 = *(const bf16x8*)&yr[l * 8];
    bf16x8 c0 = *(const bf16x8*)&zr[l * 8];
    bf16x4 a1 = *(const bf16x4*)&xr[512 + l * 4];
    bf16x4 b1 = *(const bf16x4*)&yr[512 + l * 4];
    bf16x4 c1 = *(const bf16x4*)&zr[512 + l * 4];

    float v[12], s = 0.f, sq = 0.f;
#pragma unroll
    for (int i = 0; i < 8; ++i) {
        float t = (float)a0[i] + (float)b0[i] + (float)c0[i];
        v[i] = t; s += t; sq += t * t;
    }
#pragma unroll
    for (int i = 0; i < 4; ++i) {
        float t = (float)a1[i] + (float)b1[i] + (float)c1[i];
        v[8 + i] = t; s += t; sq += t * t;
    }
#pragma unroll
    for (int off = 32; off; off >>= 1) {
        s += __shfl_xor(s, off);
        sq += __shfl_xor(sq, off);
    }
    const float mean = s * (1.f / 768.f);
    const float var = sq * (1.f / 768.f) - mean * mean;
    const float rs = rsqrtf(var + 1e-12f);

    f32x4 g0 = *(const f32x4*)&g[l * 8];
    f32x4 g1 = *(const f32x4*)&g[l * 8 + 4];
    f32x4 g2 = *(const f32x4*)&g[512 + l * 4];
    f32x4 p0 = *(const f32x4*)&bb[l * 8];
    f32x4 p1 = *(const f32x4*)&bb[l * 8 + 4];
    f32x4 p2 = *(const f32x4*)&bb[512 + l * 4];

    bf16x8 o0;
    bf16x4 o1;
#pragma unroll
    for (int i = 0; i < 4; ++i) {
        o0[i]     = (bf16)((v[i]     - mean) * rs * g0[i] + p0[i]);
        o0[4 + i] = (bf16)((v[4 + i] - mean) * rs * g1[i] + p1[i]);
        o1[i]     = (bf16)((v[8 + i] - mean) * rs * g2[i] + p2[i]);
    }
    bf16* orow = Out + (size_t)row * DD;
    *(bf16x8*)&orow[l * 8] = o0;
    *(bf16x4*)&orow[512 + l * 4] = o1;
}

// d_out[b][t][d] = x[b][TSPLIT+t][d]  (fp32 out), vectorized x8
__global__ void copy_out(const bf16* __restrict__ x, float* __restrict__ out)
{
    const size_t i8 = ((size_t)blockIdx.x * 256 + threadIdx.x) * 8;  // < 16*352*768
    const int d = (int)(i8 % DD);
    const size_t row = i8 / DD;
    const int t = (int)(row % TT);
    const int b = (int)(row / TT);
    bf16x8 v = *(const bf16x8*)&x[((size_t)b * LSEQ + TSPLIT + t) * DD + d];
    f32x4 o0, o1;
#pragma unroll
    for (int j = 0; j < 4; ++j) { o0[j] = (float)v[j]; o1[j] = (float)v[4 + j]; }
    *(f32x4*)&out[i8] = o0;
    *(f32x4*)&out[i8 + 4] = o1;
}

// ---------------------------------------------------------------------------
// host side
// ---------------------------------------------------------------------------
static void launch_gemm(const bf16* A, const bf16* Bt, bf16* C, const float* bias,
                        int M, int K, int lda, int ldb, int ldc,
                        float alpha, int Nstore, int act, int ksplit, size_t zstride,
                        hipStream_t stream)
{
    dim3 grid((Nstore + 127) / 128, M / 128, ksplit);
    if (act)
        gemm_bt<1><<<grid, 256, 0, stream>>>(A, Bt, C, bias, K / ksplit, lda, ldb, ldc, alpha, Nstore, zstride);
    else
        gemm_bt<0><<<grid, 256, 0, stream>>>(A, Bt, C, bias, K / ksplit, lda, ldb, ldc, alpha, Nstore, zstride);
}

static void launch_gemm8(const bf16* A, const bf16* Bt, bf16* C, const float* bias,
                         int M, int K, int lda, int ldb, int ldc,
                         float alpha, int Nstore, int act, hipStream_t stream)
{
    dim3 grid((Nstore + 127) / 128, M / 256, 1);
    if (act)
        gemm_bt8<1><<<grid, 512, 0, stream>>>(A, Bt, C, bias, K, lda, ldb, ldc, alpha, Nstore);
    else
        gemm_bt8<0><<<grid, 512, 0, stream>>>(A, Bt, C, bias, K, lda, ldb, ldc, alpha, Nstore);
}

extern "C" void kernel_launch(void* const* d_in, const int* in_sizes, int n_in,
                              void* d_out, int out_size, void* d_ws, size_t ws_size,
                              hipStream_t stream)
{
    const float* gnf     = (const float*)d_in[0];
    const float* text    = (const float*)d_in[1];
    const int*   tatts   = (const int*)d_in[2];
    const int*   gmask   = (const int*)d_in[3];
    const float* qtok    = (const float*)d_in[4];
    const float* gproj_w = (const float*)d_in[5];
    const float* gproj_b = (const float*)d_in[6];
    const float* pos     = (const float*)d_in[7];
    const float* tok     = (const float*)d_in[8];
    const float* eg      = (const float*)d_in[9];
    const float* eb      = (const float*)d_in[10];
    const float* qkv_w   = (const float*)d_in[11];
    const float* qkv_b   = (const float*)d_in[12];
    const float* ao_w    = (const float*)d_in[13];
    const float* ao_b    = (const float*)d_in[14];
    const float* ln1g    = (const float*)d_in[15];
    const float* ln1b    = (const float*)d_in[16];
    const float* ff1_w   = (const float*)d_in[17];
    const float* ff1_b   = (const float*)d_in[18];
    const float* ff2_w   = (const float*)d_in[19];
    const float* ff2_b   = (const float*)d_in[20];
    const float* ln2g    = (const float*)d_in[21];
    const float* ln2b    = (const float*)d_in[22];
    float* out = (float*)d_out;

    // ws layout (bf16 elems), total 57,409,536 = 114.8 MB (ws >= 169 MB).
    // u-region: qkvb (attn) / hbuf (ffn), disjoint in time. t2 sits past the
    // full u region so split-K z=1 writes never alias a GEMM's A operand.
    bf16* ws   = (bf16*)d_ws;
    bf16* wq   = ws;                    // 1,769,472  (qkv_w^T)
    bf16* wa   = wq + 1769472;          //   589,824  (ao_w^T)
    bf16* w1   = wa + 589824;           // 2,359,296  (ff1_w^T; gproj^T pre-loop)
    bf16* w2   = w1 + 2359296;          // 2,359,296  (ff2_w^T)
    bf16* x    = w2 + 2359296;          // 6,291,456
    bf16* ctx  = x   + 6291456;         // 6,291,456
    bf16* t1   = ctx + 6291456;         // 6,291,456
    bf16* u    = t1  + 6291456;         // 25,165,824
    bf16* qkvb = u;                     //   18,874,368 (attn phase)
    bf16* hbuf = u;                     //   25,165,824 (ffn phase)
    bf16* t2   = u   + 25165824;        // 6,291,456 (split-K partial z=1)
    bf16* gfeat = t1;                   //    1,572,864 (pre-loop)
    bf16* gnfb  = u;                    //    1,572,864 (pre-loop)
    const size_t ZST = (size_t)(t2 - t1);   // 31,457,280 elems

    dim3 blk(256);

    // graph projection: gfeat[2048,768] = bf16(gnf) @ bf16(gproj_w) + b
    cvt_bf16<<<6144, blk, 0, stream>>>(gnf, gnfb, 1572864);
    transpose_w<<<dim3(24, 24), blk, 0, stream>>>(gproj_w, w1, 768, 768);
    launch_gemm(gnfb, w1, gfeat, gproj_b, 2048, 768, 768, 768, 768,
                1.f, 768, 0, 1, 0, stream);
    embed_ln<<<8192, blk, 0, stream>>>(qtok, gfeat, text, pos, tok, eg, eb, x);

    for (int i = 0; i < NLAYER; ++i) {
        // all weight transposes for this layer in one launch
        transpose_all<<<6912, blk, 0, stream>>>(
            qkv_w + (size_t)i * 768 * 2304, ao_w + (size_t)i * 589824,
            ff1_w + (size_t)i * 2359296,    ff2_w + (size_t)i * 2359296,
            wq, wa, w1, w2);

        // qkv = x @ qkv_w[i] + b   [8192, 2304]  (128^2 kernel: better tail)
        launch_gemm(x, wq, qkvb, qkv_b + i * 2304,
                    8192, 768, 768, 768, 2304, 1.f, 2304, 0, 1, 0, stream);
        // fused attention -> ctx [8192, 768]
        flash_attn<<<dim3(8, 128), blk, 0, stream>>>(qkvb, ctx, tatts, gmask);
        // t1/t2 = split-K partials of ctx @ ao_w[i] (+ b at z=0)
        launch_gemm(ctx, wa, t1, ao_b + i * 768,
                    8192, 768, 768, 768, 768, 1.f, 768, 0, 2, ZST, stream);
        ln_rows3<<<2048, blk, 0, stream>>>(x, t1, t2, x, ln1g + i * 768, ln1b + i * 768);

        // ffn
        launch_gemm8(x, w1, hbuf, ff1_b + i * 3072,
                     8192, 768, 768, 768, 3072, 1.f, 3072, 1, stream);
        launch_gemm(hbuf, w2, t1, ff2_b + i * 768,
                    8192, 3072, 3072, 3072, 768, 1.f, 768, 0, 2, ZST, stream);
        ln_rows3<<<2048, blk, 0, stream>>>(x, t1, t2, x, ln2g + i * 768, ln2b + i * 768);
    }

    copy_out<<<2112, blk, 0, stream>>>(x, out);

    (void)in_sizes; (void)n_in; (void)out_size; (void)ws_size;
}